// Round 7
// baseline (238.360 us; speedup 1.0000x reference)
//
#include <hip/hip_runtime.h>
#include <stdint.h>

#define NUM_KP 17
#define BATCH  32
#define HDIM   256
#define WDIM   256
#define NCH    (BATCH * NUM_KP)     // 544 channels
#define MAXP   30
#define THREADS 512                 // 8 waves/block; 3 blocks/CU -> all 544 resident
#define NWAVES  8
#define SEGCAP  1280                // per-wave candidate segment (E~918, sigma~29 -> +12 sigma)

// 12-bit score quantization: q = (float_bits >> 13) - QB, clamped [1, 4095].
// Scores in (0.1, 1] -> q in [613, 4095]; ~64 candidates in top bin -> survivors ~94.
#define NBINS  4096
#define QB     125953               // (0x3F800000 >> 13) - 4095

__device__ __forceinline__ unsigned long long shfl_down_u64(unsigned long long v, int off) {
    unsigned lo = (unsigned)v, hi = (unsigned)(v >> 32);
    lo = __shfl_down(lo, off);
    hi = __shfl_down(hi, off);
    return ((unsigned long long)hi << 32) | lo;
}
__device__ __forceinline__ unsigned long long shfl_u64(unsigned long long v, int lane) {
    unsigned lo = (unsigned)v, hi = (unsigned)(v >> 32);
    lo = __shfl(lo, lane);
    hi = __shfl(hi, lane);
    return ((unsigned long long)hi << 32) | lo;
}
__device__ __forceinline__ unsigned quant12(float v) {
    int b = (int)(__float_as_uint(v) >> 13) - QB;
    b = b < 1 ? 1 : (b > NBINS - 1 ? NBINS - 1 : b);
    return (unsigned)b;
}

// One block per channel. LDS: 40K seg-buf + 8K packed hist + 1K gsum + 2K ref
// + ctl ~= 51.3 KB -> 3 blocks/CU, all 544 blocks co-resident.
__global__ __launch_bounds__(THREADS, 6)
void pose_fused_kernel(const float* __restrict__ heat, float* __restrict__ out, int out_size) {
    __shared__ unsigned s_buf[NWAVES * SEGCAP];  // (q12 << 16) | pixel_idx, per-wave segments
    __shared__ unsigned s_hist[NBINS / 2];       // packed u16 pairs: bin b -> word b>>1, half b&1
    __shared__ int s_gsum[256];                  // each = sum of 16 bins
    __shared__ unsigned long long s_ref[256];    // exact keys
    __shared__ int s_wcnt[NWAVES];
    __shared__ int s_nref, s_tau;

    const int tid  = threadIdx.x;
    const int chan = blockIdx.x;
    const int wave = tid >> 6;
    const int lane = tid & 63;
    const float NEGINF = -__builtin_inff();
    const float* __restrict__ cp = heat + (size_t)chan * (HDIM * WDIM);

    for (int i = tid; i < NBINS / 2; i += THREADS) s_hist[i] = 0;
    if (tid == 0) s_nref = 0;
    __syncthreads();

    // ---- Phase 1: NMS. Wave w streams rows [32w, 32w+32), groups of 4 with
    //      prefetch. Append to PRIVATE wave segment: count replicated in
    //      registers (ballot-uniform) -> no LDS atomic-with-return, no bcast. ----
    const int r0 = wave << 5;
    const float* colp = cp + (lane << 2);
    const float4 NEG4 = make_float4(NEGINF, NEGINF, NEGINF, NEGINF);
    const unsigned long long ltmask = (1ull << lane) - 1ull;
    unsigned* __restrict__ seg = s_buf + wave * SEGCAP;
    int wavecnt = 0;

    auto LD = [&](int r) -> float4 {
        return (r >= 0 && r < HDIM) ? *(const float4*)(colp + (r << 8)) : NEG4;
    };
    auto push = [&](float v, int pidx, int pos) {
        if (pos < SEGCAP) {
            unsigned q = quant12(v);
            seg[pos] = (q << 16) | (unsigned)pidx;
            atomicAdd(&s_hist[q >> 1], 1u << ((q & 1) << 4));  // fire-and-forget
        }
    };
    auto process = [&](const float4& up, const float4& md, const float4& dn, int r) {
        float vm0 = fmaxf(up.x, fmaxf(md.x, dn.x));
        float vm1 = fmaxf(up.y, fmaxf(md.y, dn.y));
        float vm2 = fmaxf(up.z, fmaxf(md.z, dn.z));
        float vm3 = fmaxf(up.w, fmaxf(md.w, dn.w));
        float left  = __shfl_up(vm3, 1);   if (lane == 0)  left  = NEGINF;
        float right = __shfl_down(vm0, 1); if (lane == 63) right = NEGINF;
        float h0 = fmaxf(left, fmaxf(vm0, vm1));
        float h1 = fmaxf(vm0, fmaxf(vm1, vm2));
        float h2 = fmaxf(vm1, fmaxf(vm2, vm3));
        float h3 = fmaxf(vm2, fmaxf(vm3, right));

        bool p0 = md.x > 0.1f && md.x == h0;
        bool p1 = md.y > 0.1f && md.y == h1;
        bool p2 = md.z > 0.1f && md.z == h2;
        bool p3 = md.w > 0.1f && md.w == h3;
        unsigned long long b0 = __ballot(p0), b1 = __ballot(p1);
        unsigned long long b2 = __ballot(p2), b3 = __ballot(p3);
        int c0 = __popcll(b0), c1 = __popcll(b1), c2 = __popcll(b2);
        int before = wavecnt;
        wavecnt += c0 + c1 + c2 + __popcll(b3);   // uniform across lanes

        const int base = (r << 8) | (lane << 2);
        if (p0) push(md.x, base + 0, before + __popcll(b0 & ltmask));
        if (p1) push(md.y, base + 1, before + c0 + __popcll(b1 & ltmask));
        if (p2) push(md.z, base + 2, before + c0 + c1 + __popcll(b2 & ltmask));
        if (p3) push(md.w, base + 3, before + c0 + c1 + c2 + __popcll(b3 & ltmask));
    };

    float4 rm   = LD(r0 - 1);
    float4 cur0 = LD(r0 + 0), cur1 = LD(r0 + 1), cur2 = LD(r0 + 2), cur3 = LD(r0 + 3);
    #pragma unroll
    for (int g = 0; g < 8; ++g) {
        const int rb = r0 + (g << 2);
        float4 n0, n1, n2, n3;
        if (g < 7) { n0 = LD(rb + 4); n1 = LD(rb + 5); n2 = LD(rb + 6); n3 = LD(rb + 7); }
        else       { n0 = LD(rb + 4); n1 = NEG4; n2 = NEG4; n3 = NEG4; }
        process(rm,   cur0, cur1, rb + 0);
        process(cur0, cur1, cur2, rb + 1);
        process(cur1, cur2, cur3, rb + 2);
        process(cur2, cur3, n0,   rb + 3);
        rm = cur3; cur0 = n0; cur1 = n1; cur2 = n2; cur3 = n3;
    }
    if (lane == 0) s_wcnt[wave] = wavecnt < SEGCAP ? wavecnt : SEGCAP;
    __syncthreads();

    // ---- Phase 2: parallel suffix scan -> bin threshold tau (rank MAXP) ----
    if (tid < 256) {            // group g = bins [16g, 16g+16) = packed words [8g, 8g+8)
        int s = 0;
        #pragma unroll
        for (int j = 0; j < 8; ++j) {
            unsigned w = s_hist[tid * 8 + j];
            s += (int)(w & 0xFFFFu) + (int)(w >> 16);
        }
        s_gsum[tid] = s;
    }
    __syncthreads();
    if (wave == 0) {            // one-wave suffix scan over 256 group sums
        int u0 = s_gsum[(lane << 2) + 0], u1 = s_gsum[(lane << 2) + 1];
        int u2 = s_gsum[(lane << 2) + 2], u3 = s_gsum[(lane << 2) + 3];
        int t = u0 + u1 + u2 + u3;
        int R = t;
        #pragma unroll
        for (int off = 1; off < 64; off <<= 1) {
            int v = __shfl_down(R, off);
            if (lane + off < 64) R += v;
        }
        int E = R - t;                       // sum over lanes > me
        int sg3 = u3 + E, sg2 = u2 + sg3, sg1 = u1 + sg2, sg0 = u0 + sg1;
        unsigned long long mask = __ballot(sg0 >= MAXP);
        if (mask == 0ull) {
            if (lane == 0) s_tau = 0;        // fewer than MAXP total -> collect all
        } else {
            int hi = 63 - __builtin_clzll(mask);
            if (lane == hi) {
                int k, above;
                if      (sg3 >= MAXP) { k = 3; above = E;   }
                else if (sg2 >= MAXP) { k = 2; above = sg3; }
                else if (sg1 >= MAXP) { k = 1; above = sg2; }
                else                  { k = 0; above = sg1; }
                int g = (lane << 2) + k;
                int cum = above, tau = 0;
                for (int b = (g << 4) + 15; b >= (g << 4); --b) {
                    cum += (int)((s_hist[b >> 1] >> ((b & 1) << 4)) & 0xFFFFu);
                    if (cum >= MAXP) { tau = b; break; }
                }
                s_tau = tau;
            }
        }
    }
    __syncthreads();

    // ---- Phase 3: collect survivors (q >= tau), re-read exact scores (~94) ----
    const unsigned tau = (unsigned)s_tau;
    for (int s = 0; s < NWAVES; ++s) {
        const int c = s_wcnt[s];
        const unsigned* sb = s_buf + s * SEGCAP;
        for (int i = tid; i < c; i += THREADS) {
            unsigned p = sb[i];
            if ((p >> 16) >= tau) {
                int pos = atomicAdd(&s_nref, 1);
                if (pos < 256) {
                    unsigned idx = p & 0xFFFFu;
                    float sc = cp[idx];
                    // key: higher score wins; tie -> smaller idx (matches lax.top_k)
                    s_ref[pos] = ((unsigned long long)__float_as_uint(sc) << 32) | (unsigned)(~idx);
                }
            }
        }
    }
    __syncthreads();
    const int nref = s_nref < 256 ? s_nref : 256;

    // ---- Phase 4: exact top-30 extraction, wave 0 only ----
    if (tid < 64) {
        unsigned long long k0 = (tid       < nref) ? s_ref[tid]       : 0ull;
        unsigned long long k1 = (tid + 64  < nref) ? s_ref[tid + 64]  : 0ull;
        unsigned long long k2 = (tid + 128 < nref) ? s_ref[tid + 128] : 0ull;
        unsigned long long k3 = (tid + 192 < nref) ? s_ref[tid + 192] : 0ull;
        for (int r = 0; r < MAXP; ++r) {
            unsigned long long best = k0; int bs = 0;
            if (k1 > best) { best = k1; bs = 1; }
            if (k2 > best) { best = k2; bs = 2; }
            if (k3 > best) { best = k3; bs = 3; }
            unsigned long long key = best;
            int slot = (bs << 6) | tid;
            #pragma unroll
            for (int off = 32; off > 0; off >>= 1) {
                unsigned long long ok = shfl_down_u64(key, off);
                int os = __shfl_down(slot, off);
                if (ok > key) { key = ok; slot = os; }
            }
            key  = shfl_u64(key, 0);
            slot = __shfl(slot, 0);
            if ((slot & 63) == tid) {           // winner's owner removes it
                int which = slot >> 6;
                if      (which == 0) k0 = 0ull;
                else if (which == 1) k1 = 0ull;
                else if (which == 2) k2 = 0ull;
                else                 k3 = 0ull;
            }
            if (tid == 0) {
                float sc, vld; unsigned idx;
                if (key != 0ull) {
                    sc  = __uint_as_float((unsigned)(key >> 32));
                    idx = (~(unsigned)key) & 0xFFFFu;
                    vld = 1.0f;
                } else { sc = NEGINF; idx = 0u; vld = 0.0f; }
                int x = (int)(idx & 255), y = (int)(idx >> 8);
                long long cb = ((long long)chan * MAXP + r) * 2;
                if (cb + 1 < out_size) {
                    out[cb]     = (float)(x * 4);   // (x, y) * STRIDE
                    out[cb + 1] = (float)(y * 4);
                }
                long long so = (long long)NCH * MAXP * 2 + (long long)chan * MAXP + r;
                if (so < out_size) out[so] = sc;
                long long vo = (long long)NCH * MAXP * 3 + (long long)chan * MAXP + r;
                if (vo < out_size) out[vo] = vld;
            }
        }
    }
}

extern "C" void kernel_launch(void* const* d_in, const int* in_sizes, int n_in,
                              void* d_out, int out_size, void* d_ws, size_t ws_size,
                              hipStream_t stream) {
    const float* heat = (const float*)d_in[0];
    float* out = (float*)d_out;
    hipLaunchKernelGGL(pose_fused_kernel, dim3(NCH), dim3(THREADS), 0, stream, heat, out, out_size);
}

// Round 8
// 237.615 us; speedup vs baseline: 1.0031x; 1.0031x over previous
//
#include <hip/hip_runtime.h>
#include <stdint.h>

#define NUM_KP 17
#define BATCH  32
#define HDIM   256
#define WDIM   256
#define NCH    (BATCH * NUM_KP)     // 544 channels
#define MAXP   30
#define QBLKS  4                    // quarter-channels -> 2176 blocks in kernel 1
#define K1THREADS 256               // 4 waves/block
#define SEGCAP 640                  // per-wave candidate segment (E~459, +9 sigma)

// 12-bit score quantization: q = (float_bits >> 13) - QB, clamped [1, 4095].
// Scores in (0.1, 1] -> q in [613, 4095]; per quarter ~16 in top bin -> survivors ~46.
#define NBINS  4096
#define QB     125953               // (0x3F800000 >> 13) - 4095

// ws: 2176 blocks x 30 keys x 8 B = 522 KB of partial top-30 keys.
#define WS_REQUIRED ((size_t)NCH * QBLKS * MAXP * 8)

__device__ __forceinline__ unsigned long long shfl_down_u64(unsigned long long v, int off) {
    unsigned lo = (unsigned)v, hi = (unsigned)(v >> 32);
    lo = __shfl_down(lo, off);
    hi = __shfl_down(hi, off);
    return ((unsigned long long)hi << 32) | lo;
}
__device__ __forceinline__ unsigned long long shfl_u64(unsigned long long v, int lane) {
    unsigned lo = (unsigned)v, hi = (unsigned)(v >> 32);
    lo = __shfl(lo, lane);
    hi = __shfl(hi, lane);
    return ((unsigned long long)hi << 32) | lo;
}
__device__ __forceinline__ unsigned quant12(float v) {
    int b = (int)(__float_as_uint(v) >> 13) - QB;
    b = b < 1 ? 1 : (b > NBINS - 1 ? NBINS - 1 : b);
    return (unsigned)b;
}

// ---- Kernel 1: quarter-channel NMS + partial exact top-30 -> ws keys ----
// LDS ~= 10.2K seg + 8K hist + 1K gsum + 2K ref + ctl ~= 21.5 KB -> 7 blocks/CU
// (28 waves/CU resident; 2176 blocks = 8.5 blocks/CU -> low tail imbalance).
__global__ __launch_bounds__(K1THREADS, 7)
void pose_part_kernel(const float* __restrict__ heat, unsigned long long* __restrict__ part) {
    __shared__ unsigned s_buf[4 * SEGCAP];       // (q12 << 16) | pixel_idx, per-wave segments
    __shared__ unsigned s_hist[NBINS / 2];       // packed u16 pairs
    __shared__ int s_gsum[256];                  // each = sum of 16 bins
    __shared__ unsigned long long s_ref[256];    // exact survivor keys
    __shared__ int s_wcnt[4];
    __shared__ int s_nref, s_tau;

    const int tid  = threadIdx.x;
    const int chan = blockIdx.x >> 2;
    const int qtr  = blockIdx.x & 3;
    const int wave = tid >> 6;
    const int lane = tid & 63;
    const float NEGINF = -__builtin_inff();
    const float* __restrict__ cp = heat + (size_t)chan * (HDIM * WDIM);

    for (int i = tid; i < NBINS / 2; i += K1THREADS) s_hist[i] = 0;
    if (tid == 0) s_nref = 0;
    __syncthreads();

    // ---- Phase 1: NMS over this wave's 16 rows (groups of 4, 1-group prefetch) ----
    const int r0 = (qtr << 6) + (wave << 4);
    const float* colp = cp + (lane << 2);
    const float4 NEG4 = make_float4(NEGINF, NEGINF, NEGINF, NEGINF);
    const unsigned long long ltmask = (1ull << lane) - 1ull;
    unsigned* __restrict__ seg = s_buf + wave * SEGCAP;
    int wavecnt = 0;

    auto LD = [&](int r) -> float4 {
        return (r >= 0 && r < HDIM) ? *(const float4*)(colp + (r << 8)) : NEG4;
    };
    auto push = [&](float v, int pidx, int pos) {
        if (pos < SEGCAP) {
            unsigned q = quant12(v);
            seg[pos] = (q << 16) | (unsigned)pidx;
            atomicAdd(&s_hist[q >> 1], 1u << ((q & 1) << 4));  // fire-and-forget
        }
    };
    auto process = [&](const float4& up, const float4& md, const float4& dn, int r) {
        float vm0 = fmaxf(up.x, fmaxf(md.x, dn.x));
        float vm1 = fmaxf(up.y, fmaxf(md.y, dn.y));
        float vm2 = fmaxf(up.z, fmaxf(md.z, dn.z));
        float vm3 = fmaxf(up.w, fmaxf(md.w, dn.w));
        float left  = __shfl_up(vm3, 1);   if (lane == 0)  left  = NEGINF;
        float right = __shfl_down(vm0, 1); if (lane == 63) right = NEGINF;
        float h0 = fmaxf(left, fmaxf(vm0, vm1));
        float h1 = fmaxf(vm0, fmaxf(vm1, vm2));
        float h2 = fmaxf(vm1, fmaxf(vm2, vm3));
        float h3 = fmaxf(vm2, fmaxf(vm3, right));

        bool p0 = md.x > 0.1f && md.x == h0;
        bool p1 = md.y > 0.1f && md.y == h1;
        bool p2 = md.z > 0.1f && md.z == h2;
        bool p3 = md.w > 0.1f && md.w == h3;
        unsigned long long b0 = __ballot(p0), b1 = __ballot(p1);
        unsigned long long b2 = __ballot(p2), b3 = __ballot(p3);
        int c0 = __popcll(b0), c1 = __popcll(b1), c2 = __popcll(b2);
        int before = wavecnt;
        wavecnt += c0 + c1 + c2 + __popcll(b3);   // wave-uniform

        const int base = (r << 8) | (lane << 2);
        if (p0) push(md.x, base + 0, before + __popcll(b0 & ltmask));
        if (p1) push(md.y, base + 1, before + c0 + __popcll(b1 & ltmask));
        if (p2) push(md.z, base + 2, before + c0 + c1 + __popcll(b2 & ltmask));
        if (p3) push(md.w, base + 3, before + c0 + c1 + c2 + __popcll(b3 & ltmask));
    };

    float4 rm   = LD(r0 - 1);
    float4 cur0 = LD(r0 + 0), cur1 = LD(r0 + 1), cur2 = LD(r0 + 2), cur3 = LD(r0 + 3);
    #pragma unroll
    for (int g = 0; g < 4; ++g) {
        const int rb = r0 + (g << 2);
        float4 n0, n1, n2, n3;
        if (g < 3) { n0 = LD(rb + 4); n1 = LD(rb + 5); n2 = LD(rb + 6); n3 = LD(rb + 7); }
        else       { n0 = LD(rb + 4); n1 = NEG4; n2 = NEG4; n3 = NEG4; }
        process(rm,   cur0, cur1, rb + 0);
        process(cur0, cur1, cur2, rb + 1);
        process(cur1, cur2, cur3, rb + 2);
        process(cur2, cur3, n0,   rb + 3);
        rm = cur3; cur0 = n0; cur1 = n1; cur2 = n2; cur3 = n3;
    }
    if (lane == 0) s_wcnt[wave] = wavecnt < SEGCAP ? wavecnt : SEGCAP;
    __syncthreads();

    // ---- Phase 2: parallel suffix scan -> bin threshold tau (rank MAXP) ----
    {
        int s = 0;
        #pragma unroll
        for (int j = 0; j < 8; ++j) {
            unsigned w = s_hist[tid * 8 + j];
            s += (int)(w & 0xFFFFu) + (int)(w >> 16);
        }
        s_gsum[tid] = s;
    }
    __syncthreads();
    if (wave == 0) {            // one-wave suffix scan over 256 group sums
        int u0 = s_gsum[(lane << 2) + 0], u1 = s_gsum[(lane << 2) + 1];
        int u2 = s_gsum[(lane << 2) + 2], u3 = s_gsum[(lane << 2) + 3];
        int t = u0 + u1 + u2 + u3;
        int R = t;
        #pragma unroll
        for (int off = 1; off < 64; off <<= 1) {
            int v = __shfl_down(R, off);
            if (lane + off < 64) R += v;
        }
        int E = R - t;                       // sum over lanes > me
        int sg3 = u3 + E, sg2 = u2 + sg3, sg1 = u1 + sg2, sg0 = u0 + sg1;
        unsigned long long mask = __ballot(sg0 >= MAXP);
        if (mask == 0ull) {
            if (lane == 0) s_tau = 0;        // fewer than MAXP total -> collect all
        } else {
            int hi = 63 - __builtin_clzll(mask);
            if (lane == hi) {
                int k, above;
                if      (sg3 >= MAXP) { k = 3; above = E;   }
                else if (sg2 >= MAXP) { k = 2; above = sg3; }
                else if (sg1 >= MAXP) { k = 1; above = sg2; }
                else                  { k = 0; above = sg1; }
                int g = (lane << 2) + k;
                int cum = above, tau = 0;
                for (int b = (g << 4) + 15; b >= (g << 4); --b) {
                    cum += (int)((s_hist[b >> 1] >> ((b & 1) << 4)) & 0xFFFFu);
                    if (cum >= MAXP) { tau = b; break; }
                }
                s_tau = tau;
            }
        }
    }
    __syncthreads();

    // ---- Phase 3: collect survivors (q >= tau), re-read exact scores (~46) ----
    const unsigned tau = (unsigned)s_tau;
    for (int s = 0; s < 4; ++s) {
        const int c = s_wcnt[s];
        const unsigned* sb = s_buf + s * SEGCAP;
        for (int i = tid; i < c; i += K1THREADS) {
            unsigned p = sb[i];
            if ((p >> 16) >= tau) {
                int pos = atomicAdd(&s_nref, 1);
                if (pos < 256) {
                    unsigned idx = p & 0xFFFFu;
                    float sc = cp[idx];
                    // key: higher score wins; tie -> smaller idx (matches lax.top_k)
                    s_ref[pos] = ((unsigned long long)__float_as_uint(sc) << 32) | (unsigned)(~idx);
                }
            }
        }
    }
    __syncthreads();
    const int nref = s_nref < 256 ? s_nref : 256;

    // ---- Phase 4: partial exact top-30, wave 0; write keys to ws ----
    if (tid < 64) {
        unsigned long long* pk = part + (size_t)blockIdx.x * MAXP;
        unsigned long long k0 = (tid       < nref) ? s_ref[tid]       : 0ull;
        unsigned long long k1 = (tid + 64  < nref) ? s_ref[tid + 64]  : 0ull;
        unsigned long long k2 = (tid + 128 < nref) ? s_ref[tid + 128] : 0ull;
        unsigned long long k3 = (tid + 192 < nref) ? s_ref[tid + 192] : 0ull;
        for (int r = 0; r < MAXP; ++r) {
            unsigned long long best = k0; int bs = 0;
            if (k1 > best) { best = k1; bs = 1; }
            if (k2 > best) { best = k2; bs = 2; }
            if (k3 > best) { best = k3; bs = 3; }
            unsigned long long key = best;
            int slot = (bs << 6) | tid;
            #pragma unroll
            for (int off = 32; off > 0; off >>= 1) {
                unsigned long long ok = shfl_down_u64(key, off);
                int os = __shfl_down(slot, off);
                if (ok > key) { key = ok; slot = os; }
            }
            key  = shfl_u64(key, 0);
            slot = __shfl(slot, 0);
            if ((slot & 63) == tid) {           // winner's owner removes it
                int which = slot >> 6;
                if      (which == 0) k0 = 0ull;
                else if (which == 1) k1 = 0ull;
                else if (which == 2) k2 = 0ull;
                else                 k3 = 0ull;
            }
            if (tid == 0) pk[r] = key;          // 0 = empty slot
        }
    }
}

// ---- Kernel 2: merge 4 x 30 partial keys per channel -> final outputs ----
__global__ __launch_bounds__(64)
void pose_merge_kernel(const unsigned long long* __restrict__ part,
                       float* __restrict__ out, int out_size) {
    const int chan = blockIdx.x;
    const int lane = threadIdx.x;
    const float NEGINF = -__builtin_inff();
    const unsigned long long* pk = part + (size_t)chan * (QBLKS * MAXP);  // 120 keys

    unsigned long long k0 = pk[lane];                                  // 120 > 64
    unsigned long long k1 = (lane + 64 < QBLKS * MAXP) ? pk[lane + 64] : 0ull;

    for (int r = 0; r < MAXP; ++r) {
        unsigned long long best = k0; int bs = 0;
        if (k1 > best) { best = k1; bs = 1; }
        unsigned long long key = best;
        int slot = (bs << 6) | lane;
        #pragma unroll
        for (int off = 32; off > 0; off >>= 1) {
            unsigned long long ok = shfl_down_u64(key, off);
            int os = __shfl_down(slot, off);
            if (ok > key) { key = ok; slot = os; }
        }
        key  = shfl_u64(key, 0);
        slot = __shfl(slot, 0);
        if ((slot & 63) == lane) {
            if ((slot >> 6) == 0) k0 = 0ull; else k1 = 0ull;
        }
        if (lane == 0) {
            float sc, vld; unsigned idx;
            if (key != 0ull) {
                sc  = __uint_as_float((unsigned)(key >> 32));
                idx = (~(unsigned)key) & 0xFFFFu;
                vld = 1.0f;
            } else { sc = NEGINF; idx = 0u; vld = 0.0f; }
            int x = (int)(idx & 255), y = (int)(idx >> 8);
            long long cb = ((long long)chan * MAXP + r) * 2;
            if (cb + 1 < out_size) {
                out[cb]     = (float)(x * 4);   // (x, y) * STRIDE
                out[cb + 1] = (float)(y * 4);
            }
            long long so = (long long)NCH * MAXP * 2 + (long long)chan * MAXP + r;
            if (so < out_size) out[so] = sc;
            long long vo = (long long)NCH * MAXP * 3 + (long long)chan * MAXP + r;
            if (vo < out_size) out[vo] = vld;
        }
    }
}

extern "C" void kernel_launch(void* const* d_in, const int* in_sizes, int n_in,
                              void* d_out, int out_size, void* d_ws, size_t ws_size,
                              hipStream_t stream) {
    const float* heat = (const float*)d_in[0];
    float* out = (float*)d_out;
    unsigned long long* part = (unsigned long long*)d_ws;
    hipLaunchKernelGGL(pose_part_kernel, dim3(NCH * QBLKS), dim3(K1THREADS), 0, stream,
                       heat, part);
    hipLaunchKernelGGL(pose_merge_kernel, dim3(NCH), dim3(64), 0, stream,
                       part, out, out_size);
}